// Round 6
// baseline (571.193 us; speedup 1.0000x reference)
//
#include <hip/hip_runtime.h>
#include <hip/hip_cooperative_groups.h>
#include <hip/hip_bf16.h>

namespace cg = cooperative_groups;

#define NPTS 4096
#define BATCH 4
#define BN (BATCH * NPTS)
#define DMODEL 128
#define DPTS 64
#define KNBR 16
#define SWS 136   // padded LDS row stride (272B rows: 16B-aligned, balanced banks for b128)

typedef unsigned short u16;
typedef unsigned int u32;
typedef short bh8 __attribute__((ext_vector_type(8)));
typedef float f32x4 __attribute__((ext_vector_type(4)));

__device__ __forceinline__ float bfu(u16 u) {
    union { u32 i; float f; } c; c.i = ((u32)u) << 16; return c.f;
}
__device__ __forceinline__ u16 f2u(float x) {   // f32->bf16 RNE
    u32 u = __float_as_uint(x);
    u32 r = u + 0x7FFFu + ((u >> 16) & 1u);
    return (u16)(r >> 16);
}
__device__ __forceinline__ u32 pack2(float a, float b) {
    return (u32)f2u(a) | ((u32)f2u(b) << 16);
}
template<int MODE> __device__ __forceinline__ float ld(const void* p, long i) {
    if (MODE == 0) return bfu(((const u16*)p)[i]);
    return ((const float*)p)[i];
}
template<int MODE> __device__ __forceinline__ void st_out(void* p, long i, float v) {
    if (MODE == 0) ((u16*)p)[i] = f2u(v);
    else ((float*)p)[i] = v;
}

struct MegaArgs {
    const void *xyz, *feat, *Wd1, *bd1, *Wd2, *bd2, *Wf1, *bf1;
    const void *Wq, *Wk, *Wv, *Wg1, *bg1, *Wg2, *bg2, *Wo, *bo;
    u16 *WdT2, *WgT1, *WgT2, *WoT, *WqT, *WkT, *WvT, *WfT;
    u16 *qw, *kfw, *vfw;
    int *idx;
    const int* flag;
    void* out;
};

// ---------------- dtype detector ----------------------------------------------------
__global__ void detect_kernel(const u16* w, int* flag) {
    int hits = 0;
    for (int i = threadIdx.x; i < 2048; i += 64) {
        unsigned e = (w[i] >> 7) & 0xFFu;
        if (e >= 132u || (e > 0u && e <= 90u)) hits++;
    }
    for (int o = 32; o; o >>= 1) hits += __shfl_down(hits, o);
    if (threadIdx.x == 0) flag[0] = (hits > 64) ? 1 : 0;
}

// ---------------- prep: weight transposes (grid-stride, global only) ----------------
template<int MODE>
__device__ void prep_phase(const MegaArgs& a) {
    int gid = blockIdx.x * 1024 + threadIdx.x;
    if (gid < 6 * 16384) {
        int m = gid >> 14, o = gid & 16383;
        int n = o >> 7, i = o & 127;
        const void* W = (m == 0) ? a.Wd2 : (m == 1) ? a.Wg1 : (m == 2) ? a.Wg2
                      : (m == 3) ? a.Wq  : (m == 4) ? a.Wk  : a.Wv;
        u16* D = (m == 0) ? a.WdT2 : (m == 1) ? a.WgT1 : (m == 2) ? a.WgT2
               : (m == 3) ? a.WqT  : (m == 4) ? a.WkT  : a.WvT;
        D[o] = f2u(ld<MODE>(W, (long)i * 128 + n));            // W^T[n][i]
    } else if (gid < 6 * 16384 + 8192) {
        int o = gid - 6 * 16384;
        int n = o >> 6, k2 = o & 63;
        a.WfT[o] = f2u(ld<MODE>(a.Wf1, (long)k2 * 128 + n));   // Wf1^T[n][k]
    } else if (gid < 6 * 16384 + 16384) {
        int o2 = gid - 6 * 16384 - 8192;
        int col = o2 >> 7, i = o2 & 127;
        a.WoT[o2] = f2u(ld<MODE>(a.Wo, (long)i * 64 + col));   // Wo^T[col][i]
    }
}

// ---------------- knn: wave-cooperative top-16, 16 waves x 4 points each ------------
template<int MODE>
__device__ void knn_phase(const MegaArgs& a, char* smem) {
    u16* sXyz = (u16*)smem;                    // [4096][4] bf16
    float* sN2 = (float*)(smem + 32768);       // [4096]
    const int t = threadIdx.x;
    const int blk = blockIdx.x;
    const long xb = (long)((blk * 64) >> 12) * NPTS * 3;
    for (int m = t; m < NPTS; m += 1024) {
        float gx = ld<MODE>(a.xyz, xb + m * 3 + 0);
        float gy = ld<MODE>(a.xyz, xb + m * 3 + 1);
        float gz = ld<MODE>(a.xyz, xb + m * 3 + 2);
        uint2 pk;
        pk.x = (u32)f2u(gx) | ((u32)f2u(gy) << 16);
        pk.y = (u32)f2u(gz);
        *(uint2*)(sXyz + m * 4) = pk;
        sN2[m] = gx * gx + gy * gy + gz * gz;
    }
    __syncthreads();
    const int w = t >> 6, lane = t & 63;
#pragma unroll 1
    for (int rep = 0; rep < 4; ++rep) {
        const int pg = rep * 16 + w;                        // point-in-block 0..63
        const int pl = ((blk * 64) & (NPTS - 1)) + pg;
        uint2 qv = *(const uint2*)(sXyz + pl * 4);
        const float px = __uint_as_float(qv.x << 16);
        const float py = __uint_as_float(qv.x & 0xFFFF0000u);
        const float pz = __uint_as_float(qv.y << 16);
        float kd = 3e38f; int ki = 0;
        float T = 3e38f;
#pragma unroll 1
        for (int it = 0; it < NPTS / 64; ++it) {
            const int c = it * 64 + lane;
            uint2 cd = *(const uint2*)(sXyz + c * 4);
            float cx = __uint_as_float(cd.x << 16);
            float cy = __uint_as_float(cd.x & 0xFFFF0000u);
            float cz = __uint_as_float(cd.y << 16);
            float key = sN2[c] - 2.f * (px * cx + py * cy + pz * cz);
            unsigned long long mask = __ballot(key < T);
            while (mask) {
                int l = __ffsll(mask) - 1;
                mask &= mask - 1;
                float kk = __uint_as_float(__builtin_amdgcn_readlane(__float_as_uint(key), l));
                if (kk < T) {
                    int ii = it * 64 + l;
                    float pkd = __shfl_up(kd, 1);
                    int   pki = __shfl_up(ki, 1);
                    if (lane == 0) pkd = -3e38f;
                    bool pg2 = pkd > kk, cg2 = kd > kk;
                    kd = pg2 ? pkd : (cg2 ? kk : kd);
                    ki = pg2 ? pki : (cg2 ? ii : ki);
                    T = __uint_as_float(__builtin_amdgcn_readlane(__float_as_uint(kd), 15));
                }
            }
        }
        if (lane < 16) a.idx[(long)(blk * 64 + pg) * 16 + lane] = ki;
    }
}

// ---------------- qkv: 16-wave MFMA, 64 points per block ----------------------------
template<int MODE>
__device__ void qkv_phase(const MegaArgs& a, char* smem) {
    u16* sFeat = (u16*)smem;                   // 64 x 72
    u16* sW = (u16*)(smem + 9216);             // 128 x SWS
    u16* sF = (u16*)(smem + 44032);            // 64 x SWS
    const int t = threadIdx.x;
    const int p0 = blockIdx.x * 64;
    const int lane = t & 63, w = t >> 6;
    const int rg = (w & 3) * 16, cg = (w >> 2) * 32;
    const int lm = lane & 15, lq = lane >> 4;

    if (t < 512) {                              // stage feat tile [64x64]
        int r = t >> 3, c8 = t & 7;
        u16 tmp[8];
        if (MODE == 0) {
            *(uint4*)tmp = *((const uint4*)a.feat + (long)(p0 + r) * 8 + c8);
        } else {
            const float* fp = (const float*)a.feat + (long)(p0 + r) * 64 + c8 * 8;
#pragma unroll
            for (int u = 0; u < 8; ++u) tmp[u] = f2u(fp[u]);
        }
        *(uint4*)(sFeat + r * 72 + c8 * 8) = *(uint4*)tmp;
    } else {                                    // stage WfT [128x64]
        int i = t - 512;                        // 0..511, need 1024 chunks -> 2 per thread
#pragma unroll
        for (int rr = 0; rr < 2; ++rr) {
            int c = i + rr * 512;
            int r = c >> 3, c8 = c & 7;
            *(uint4*)(sW + r * SWS + c8 * 8) = ((const uint4*)a.WfT)[c];
        }
    }
    __syncthreads();

    // GEMM1: f = feat @ Wf1 + bf1 -> sF
    {
        f32x4 acc[2];
        acc[0] = {0.f,0.f,0.f,0.f}; acc[1] = {0.f,0.f,0.f,0.f};
#pragma unroll
        for (int kk = 0; kk < 2; ++kk) {
            const int ko = kk * 32 + lq * 8;
            bh8 a0 = *(const bh8*)(sFeat + (rg + lm) * 72 + ko);
            bh8 b0 = *(const bh8*)(sW + (cg + lm) * SWS + ko);
            bh8 b1 = *(const bh8*)(sW + (cg + 16 + lm) * SWS + ko);
            acc[0] = __builtin_amdgcn_mfma_f32_16x16x32_bf16(a0, b0, acc[0], 0, 0, 0);
            acc[1] = __builtin_amdgcn_mfma_f32_16x16x32_bf16(a0, b1, acc[1], 0, 0, 0);
        }
        __syncthreads();                        // sW/sFeat reads done
#pragma unroll
        for (int ct = 0; ct < 2; ++ct) {
            const int col = cg + ct * 16 + lm;
            const float bj = ld<MODE>(a.bf1, col);
#pragma unroll
            for (int r4 = 0; r4 < 4; ++r4) {
                int row = rg + lq * 4 + r4;
                u32 u = (u32)f2u(acc[ct][r4] + bj);
                u32 o = __shfl_xor(u, 1);
                if ((lane & 1) == 0)
                    *(u32*)(sF + row * SWS + col) = u | (o << 16);
            }
        }
    }
    __syncthreads();

    const u16* Ws[3] = {a.WqT, a.WkT, a.WvT};
    u16* Os[3] = {a.qw, a.kfw, a.vfw};
#pragma unroll 1
    for (int m = 0; m < 3; ++m) {
        for (int i = t; i < 2048; i += 1024) {
            int r = i >> 4, c8 = i & 15;
            *(uint4*)(sW + r * SWS + c8 * 8) = ((const uint4*)Ws[m])[i];
        }
        __syncthreads();
        f32x4 acc[2];
        acc[0] = {0.f,0.f,0.f,0.f}; acc[1] = {0.f,0.f,0.f,0.f};
#pragma unroll
        for (int kk = 0; kk < 4; ++kk) {
            const int ko = kk * 32 + lq * 8;
            bh8 a0 = *(const bh8*)(sF + (rg + lm) * SWS + ko);
            bh8 b0 = *(const bh8*)(sW + (cg + lm) * SWS + ko);
            bh8 b1 = *(const bh8*)(sW + (cg + 16 + lm) * SWS + ko);
            acc[0] = __builtin_amdgcn_mfma_f32_16x16x32_bf16(a0, b0, acc[0], 0, 0, 0);
            acc[1] = __builtin_amdgcn_mfma_f32_16x16x32_bf16(a0, b1, acc[1], 0, 0, 0);
        }
#pragma unroll
        for (int ct = 0; ct < 2; ++ct) {
            const int col = cg + ct * 16 + lm;
#pragma unroll
            for (int r4 = 0; r4 < 4; ++r4) {
                int row = rg + lq * 4 + r4;
                u32 u = (u32)f2u(acc[ct][r4]);
                u32 o = __shfl_xor(u, 1);
                if ((lane & 1) == 0)
                    *(u32*)(Os[m] + (long)(p0 + row) * DMODEL + col) = u | (o << 16);
            }
        }
        __syncthreads();                        // sW reads done before next restage
    }
}

// ---- 16-wave MFMA phase: D[128x128] = sIn @ B (+bias, opt relu) -> sOut packed -----
// Wave w: rows (w&3)*32, cols (w>>2)*32 as 2x2 tiles. B from LDS (bstride=SWS) or
// global (bstride=128).
__device__ __forceinline__ void mfma_phase16(const u16* sIn, const u16* Bm, int bstride,
                                             const float* bias, bool dorelu, bool inplace,
                                             u16* sOut, int t) {
    const int lane = t & 63, w = t >> 6;
    const int rg = (w & 3) * 32, cg = (w >> 2) * 32;
    const int lm = lane & 15, lq = lane >> 4;
    f32x4 acc[2][2];
#pragma unroll
    for (int rt = 0; rt < 2; ++rt)
#pragma unroll
        for (int ct = 0; ct < 2; ++ct) { acc[rt][ct][0]=0.f; acc[rt][ct][1]=0.f; acc[rt][ct][2]=0.f; acc[rt][ct][3]=0.f; }
#pragma unroll
    for (int kk = 0; kk < 4; ++kk) {
        const int ko = kk * 32 + lq * 8;
        bh8 a0 = *(const bh8*)(sIn + (rg + lm) * SWS + ko);
        bh8 a1 = *(const bh8*)(sIn + (rg + 16 + lm) * SWS + ko);
        bh8 b0 = *(const bh8*)(Bm + (long)(cg + lm) * bstride + ko);
        bh8 b1 = *(const bh8*)(Bm + (long)(cg + 16 + lm) * bstride + ko);
        acc[0][0] = __builtin_amdgcn_mfma_f32_16x16x32_bf16(a0, b0, acc[0][0], 0, 0, 0);
        acc[0][1] = __builtin_amdgcn_mfma_f32_16x16x32_bf16(a0, b1, acc[0][1], 0, 0, 0);
        acc[1][0] = __builtin_amdgcn_mfma_f32_16x16x32_bf16(a1, b0, acc[1][0], 0, 0, 0);
        acc[1][1] = __builtin_amdgcn_mfma_f32_16x16x32_bf16(a1, b1, acc[1][1], 0, 0, 0);
    }
    if (inplace) __syncthreads();
#pragma unroll
    for (int rt = 0; rt < 2; ++rt)
#pragma unroll
        for (int ct = 0; ct < 2; ++ct) {
            const int col = cg + ct * 16 + lm;
            const float bj = bias[col];
#pragma unroll
            for (int r4 = 0; r4 < 4; ++r4) {
                int row = rg + rt * 16 + lq * 4 + r4;
                float v = acc[rt][ct][r4] + bj;
                if (dorelu) v = fmaxf(v, 0.f);
                u32 u = (u32)f2u(v);
                u32 o = __shfl_xor(u, 1);
                if ((lane & 1) == 0)
                    *(u32*)(sOut + row * SWS + col) = u | (o << 16);
            }
        }
}

// ---------------- att: 16 waves, 8 groups x 8 points, 2 persistent weights ----------
template<int MODE>
__device__ void att_phase(const MegaArgs& a, char* smem) {
    u16* sW1  = (u16*)(smem);                  // Wd2^T (34816)
    u16* sW2  = (u16*)(smem + 34816);          // Wg1^T
    u16* sA   = (u16*)(smem + 69632);          // 128 x SWS
    u16* sPE  = (u16*)(smem + 104448);         // 128 x SWS
    u16* sRes = (u16*)(smem + 139264);         // 16 x SWS (rows 0..7 live)
    float (*sRel)[4] = (float(*)[4])(smem + 143616);   // [128][4]
    u16* sQ   = (u16*)(smem + 145664);         // 8 x 128
    float* sBias = (float*)(smem + 147712);    // bd2|bg1|bg2
    int* sIdx = (int*)(smem + 149248);         // [128]

    const int t = threadIdx.x;
    const int lane = t & 63, w = t >> 6;
    const int blk = blockIdx.x;
    const long bbase = (long)((blk * 64) >> 12) * NPTS;

    for (int i = t; i < 2048; i += 1024) {
        int r = i >> 4, c8 = i & 15;
        *(uint4*)(sW1 + r * SWS + c8 * 8) = ((const uint4*)a.WdT2)[i];
        *(uint4*)(sW2 + r * SWS + c8 * 8) = ((const uint4*)a.WgT1)[i];
    }
    if (t < 128) {
        sBias[t]       = ld<MODE>(a.bd2, t);
        sBias[128 + t] = ld<MODE>(a.bg1, t);
        sBias[256 + t] = ld<MODE>(a.bg2, t);
    }
    for (int i = t; i < 8 * SWS / 2; i += 1024) ((u32*)(sRes + 8 * SWS))[i] = 0;
    const int ch = 2 * lane;
    const float wd0a = ld<MODE>(a.Wd1, ch),       wd0b = ld<MODE>(a.Wd1, ch + 1);
    const float wd1a = ld<MODE>(a.Wd1, 128 + ch), wd1b = ld<MODE>(a.Wd1, 128 + ch + 1);
    const float wd2a = ld<MODE>(a.Wd1, 256 + ch), wd2b = ld<MODE>(a.Wd1, 256 + ch + 1);
    const float bd1a = ld<MODE>(a.bd1, ch),       bd1b = ld<MODE>(a.bd1, ch + 1);

    // stage group 0
    if (t < 128) {
        int pn = blk * 64;
        int id = a.idx[(long)pn * KNBR + t];
        sIdx[t] = id;
        long nb = bbase + id;
        int pl = t >> 4;
        sRel[t][0] = ld<MODE>(a.xyz, ((long)pn + pl) * 3 + 0) - ld<MODE>(a.xyz, nb * 3 + 0);
        sRel[t][1] = ld<MODE>(a.xyz, ((long)pn + pl) * 3 + 1) - ld<MODE>(a.xyz, nb * 3 + 1);
        sRel[t][2] = ld<MODE>(a.xyz, ((long)pn + pl) * 3 + 2) - ld<MODE>(a.xyz, nb * 3 + 2);
    }
    if (t >= 512) {
        int i = t - 512;
        ((u32*)sQ)[i] = ((const u32*)(a.qw + (long)(blk * 64) * DMODEL))[i];
    }

#pragma unroll 1
    for (int g = 0; g < 8; ++g) {
        const int p0 = blk * 64 + g * 8;
        __syncthreads();                                   // (A) staging done

        // H1 = relu(rel@Wd1+bd1) -> sA (rows w*8..+7, channel pair ch)
#pragma unroll
        for (int i = 0; i < 8; ++i) {
            int r = w * 8 + i;
            float4 rl = *(const float4*)sRel[r];
            float h0 = fmaxf(bd1a + rl.x * wd0a + rl.y * wd1a + rl.z * wd2a, 0.f);
            float h1 = fmaxf(bd1b + rl.x * wd0b + rl.y * wd1b + rl.z * wd2b, 0.f);
            *(u32*)(sA + r * SWS + ch) = pack2(h0, h1);
        }
        __syncthreads();                                   // (B)
        mfma_phase16(sA, sW1, SWS, sBias, false, false, sPE, t);   // PE
        __syncthreads();                                   // (C)

        // A = q - kf + pe -> sA
#pragma unroll
        for (int i = 0; i < 8; ++i) {
            int r = w * 8 + i;
            u32 kv2 = *(const u32*)(a.kfw + (bbase + sIdx[r]) * (long)DMODEL + ch);
            u32 qv2 = *(const u32*)(sQ + (r >> 4) * DMODEL + ch);
            u32 pe2 = *(const u32*)(sPE + r * SWS + ch);
            float a0 = bfu((u16)qv2) - bfu((u16)kv2) + bfu((u16)pe2);
            float a1 = bfu((u16)(qv2 >> 16)) - bfu((u16)(kv2 >> 16)) + bfu((u16)(pe2 >> 16));
            *(u32*)(sA + r * SWS + ch) = pack2(a0, a1);
        }
        __syncthreads();                                   // (D)
        mfma_phase16(sA, sW2, SWS, sBias + 128, true, true, sA, t);      // G
        __syncthreads();                                   // (E)
        mfma_phase16(sA, a.WgT2, 128, sBias + 256, false, true, sA, t);  // logits
        __syncthreads();                                   // (F)

        // softmax over k: wave w<8 = point w, lane = channel pair
        if (w < 8) {
            const int pl = w;
            float lg0[16], lg1[16];
            float mx0 = -3e38f, mx1 = -3e38f;
#pragma unroll
            for (int k = 0; k < KNBR; ++k) {
                u32 l2 = *(const u32*)(sA + (pl * 16 + k) * SWS + ch);
                lg0[k] = bfu((u16)l2); lg1[k] = bfu((u16)(l2 >> 16));
                mx0 = fmaxf(mx0, lg0[k]); mx1 = fmaxf(mx1, lg1[k]);
            }
            const float inv = 0.08838834764831845f;        // 1/sqrt(128)
            float s0 = 0.f, s1 = 0.f, r0 = 0.f, r1 = 0.f;
#pragma unroll
            for (int k = 0; k < KNBR; ++k) {
                u32 v2 = *(const u32*)(a.vfw + (bbase + sIdx[pl * 16 + k]) * (long)DMODEL + ch);
                u32 p2 = *(const u32*)(sPE + (pl * 16 + k) * SWS + ch);
                float e0 = __expf((lg0[k] - mx0) * inv);
                float e1 = __expf((lg1[k] - mx1) * inv);
                s0 += e0; s1 += e1;
                r0 += e0 * (bfu((u16)v2) + bfu((u16)p2));
                r1 += e1 * (bfu((u16)(v2 >> 16)) + bfu((u16)(p2 >> 16)));
            }
            *(u32*)(sRes + pl * SWS + ch) = pack2(r0 / s0, r1 / s1);
        }
        __syncthreads();                                   // (G)

        if (w < 4) {
            // out[8x64] = res @ Wo + bo + shortcut (MFMA, B from global WoT)
            const int lm = lane & 15, lq = lane >> 4;
            const int col = w * 16 + lm;
            f32x4 acc = {0.f, 0.f, 0.f, 0.f};
#pragma unroll
            for (int kk = 0; kk < 4; ++kk) {
                const int ko = kk * 32 + lq * 8;
                bh8 aa = *(const bh8*)(sRes + lm * SWS + ko);
                bh8 bb = *(const bh8*)(a.WoT + (long)col * DMODEL + ko);
                acc = __builtin_amdgcn_mfma_f32_16x16x32_bf16(aa, bb, acc, 0, 0, 0);
            }
            if (lq < 2) {
                float bov = ld<MODE>(a.bo, col);
#pragma unroll
                for (int r4 = 0; r4 < 4; ++r4) {
                    int row = lq * 4 + r4;
                    long p = p0 + row;
                    float v = acc[r4] + bov + ld<MODE>(a.feat, p * DPTS + col);
                    st_out<MODE>(a.out, p * DPTS + col, v);
                }
            }
        } else if (g + 1 < 8) {                            // stage group g+1
            int pn = blk * 64 + (g + 1) * 8;
            int j = t - 256;                               // 0..767
            if (j < 512) {
                ((u32*)sQ)[j] = ((const u32*)(a.qw + (long)pn * DMODEL))[j];
            } else {
                int i2 = j - 512;
                if (i2 < 128) {
                    int id = a.idx[(long)pn * KNBR + i2];
                    sIdx[i2] = id;
                    long nb = bbase + id;
                    int pl = i2 >> 4;
                    sRel[i2][0] = ld<MODE>(a.xyz, ((long)pn + pl) * 3 + 0) - ld<MODE>(a.xyz, nb * 3 + 0);
                    sRel[i2][1] = ld<MODE>(a.xyz, ((long)pn + pl) * 3 + 1) - ld<MODE>(a.xyz, nb * 3 + 1);
                    sRel[i2][2] = ld<MODE>(a.xyz, ((long)pn + pl) * 3 + 2) - ld<MODE>(a.xyz, nb * 3 + 2);
                }
            }
        }
    }
}

template<int MODE>
__device__ void run_all(const MegaArgs& a, char* smem) {
    cg::grid_group grid = cg::this_grid();
    prep_phase<MODE>(a);
    knn_phase<MODE>(a, smem);
    __threadfence();
    grid.sync();
    qkv_phase<MODE>(a, smem);
    __threadfence();
    grid.sync();
    att_phase<MODE>(a, smem);
}

__global__ __launch_bounds__(1024, 4) void mega_kernel(MegaArgs a) {
    __shared__ __align__(16) char smem[149760];
    if (a.flag[0] == 0) run_all<0>(a, smem);
    else                run_all<1>(a, smem);
}

extern "C" void kernel_launch(void* const* d_in, const int* in_sizes, int n_in,
                              void* d_out, int out_size, void* d_ws, size_t ws_size,
                              hipStream_t stream) {
    (void)in_sizes; (void)n_in; (void)out_size; (void)ws_size;
    char* ws = (char*)d_ws;
    int* flag = (int*)ws;
    int* idx  = (int*)(ws + 256);
    u16* qw   = (u16*)(ws + 256 + (long)BN * KNBR * 4);
    u16* kfw  = qw + (long)BN * DMODEL;
    u16* vfw  = kfw + (long)BN * DMODEL;
    u16* WdT2 = vfw + (long)BN * DMODEL;
    u16* WgT1 = WdT2 + 16384;
    u16* WgT2 = WgT1 + 16384;
    u16* WoT  = WgT2 + 16384;
    u16* WqT  = WoT + 8192;
    u16* WkT  = WqT + 16384;
    u16* WvT  = WkT + 16384;
    u16* WfT  = WvT + 16384;                  // total ws ~13.6 MB

    detect_kernel<<<1, 64, 0, stream>>>((const u16*)d_in[8], flag);

    MegaArgs ha;
    ha.xyz = d_in[0];  ha.feat = d_in[1];
    ha.Wd1 = d_in[2];  ha.bd1 = d_in[3];
    ha.Wd2 = d_in[4];  ha.bd2 = d_in[5];
    ha.Wf1 = d_in[6];  ha.bf1 = d_in[7];
    ha.Wq  = d_in[8];  ha.Wk  = d_in[9];  ha.Wv = d_in[10];
    ha.Wg1 = d_in[11]; ha.bg1 = d_in[12];
    ha.Wg2 = d_in[13]; ha.bg2 = d_in[14];
    ha.Wo  = d_in[15]; ha.bo  = d_in[16];
    ha.WdT2 = WdT2; ha.WgT1 = WgT1; ha.WgT2 = WgT2; ha.WoT = WoT;
    ha.WqT = WqT; ha.WkT = WkT; ha.WvT = WvT; ha.WfT = WfT;
    ha.qw = qw; ha.kfw = kfw; ha.vfw = vfw;
    ha.idx = idx; ha.flag = flag; ha.out = d_out;

    void* params[] = { &ha };
    hipLaunchCooperativeKernel((const void*)mega_kernel, dim3(BN / 64), dim3(1024),
                               params, 0, stream);
}

// Round 7
// 385.919 us; speedup vs baseline: 1.4801x; 1.4801x over previous
//
#include <hip/hip_runtime.h>
#include <hip/hip_bf16.h>

#define NPTS 4096
#define BATCH 4
#define BN (BATCH * NPTS)
#define DMODEL 128
#define DPTS 64
#define KNBR 16
#define SWS 136   // padded LDS row stride in bf16 elements

typedef unsigned short u16;
typedef unsigned int u32;
typedef short bh8 __attribute__((ext_vector_type(8)));
typedef float f32x4 __attribute__((ext_vector_type(4)));

__device__ __forceinline__ float bfu(u16 u) {
    union { u32 i; float f; } c; c.i = ((u32)u) << 16; return c.f;
}
__device__ __forceinline__ u16 f2u(float x) {   // f32->bf16 RNE
    u32 u = __float_as_uint(x);
    u32 r = u + 0x7FFFu + ((u >> 16) & 1u);
    return (u16)(r >> 16);
}
__device__ __forceinline__ u32 pack2(float a, float b) {
    return (u32)f2u(a) | ((u32)f2u(b) << 16);
}
// mode 0: inputs bf16; mode 1: inputs f32. Runtime-uniform, staging paths only.
__device__ __forceinline__ float ldr(const void* p, long i, int mode) {
    return mode == 0 ? bfu(((const u16*)p)[i]) : ((const float*)p)[i];
}
__device__ __forceinline__ void str(void* p, long i, float v, int mode) {
    if (mode == 0) ((u16*)p)[i] = f2u(v);
    else ((float*)p)[i] = v;
}
// Inline dtype detect: bf16 data has ~0 wild exponent fields; f32-as-u16 has ~84%.
__device__ __forceinline__ int detect_mode(const void* Wq) {
    const u16* w = (const u16*)Wq;
    int lane = threadIdx.x & 63;
    int tot = 0;
#pragma unroll
    for (int r = 0; r < 4; ++r) {
        unsigned e = (w[lane + r * 64] >> 7) & 0xFFu;
        bool wild = (e >= 132u) || (e > 0u && e <= 90u);
        tot += (int)__popcll(__ballot(wild));
    }
    return tot > 32 ? 1 : 0;
}

// ---------------- prep: weight transposes into MFMA B-layouts ------------------------
__global__ __launch_bounds__(256) void prep_kernel(
    const void* __restrict__ Wd2, const void* __restrict__ Wg1, const void* __restrict__ Wg2,
    const void* __restrict__ Wo, const void* __restrict__ Wq, const void* __restrict__ Wk,
    const void* __restrict__ Wv, const void* __restrict__ Wf1,
    u16* __restrict__ WdT2, u16* __restrict__ WgT1, u16* __restrict__ WgT2,
    u16* __restrict__ WoT, u16* __restrict__ WqT, u16* __restrict__ WkT,
    u16* __restrict__ WvT, u16* __restrict__ WfT) {
    int mode = detect_mode(Wq);
    int gid = blockIdx.x * 256 + threadIdx.x;
    if (gid < 6 * 16384) {
        int m = gid >> 14, o = gid & 16383;
        int n = o >> 7, i = o & 127;
        const void* W = (m == 0) ? Wd2 : (m == 1) ? Wg1 : (m == 2) ? Wg2
                      : (m == 3) ? Wq  : (m == 4) ? Wk  : Wv;
        u16* D = (m == 0) ? WdT2 : (m == 1) ? WgT1 : (m == 2) ? WgT2
               : (m == 3) ? WqT  : (m == 4) ? WkT  : WvT;
        D[o] = f2u(ldr(W, (long)i * 128 + n, mode));           // W^T[n][i]
    } else if (gid < 6 * 16384 + 8192) {
        int o = gid - 6 * 16384;
        int n = o >> 6, k2 = o & 63;
        WfT[o] = f2u(ldr(Wf1, (long)k2 * 128 + n, mode));      // Wf1^T[n][k]
    } else if (gid < 6 * 16384 + 16384) {
        int o2 = gid - 6 * 16384 - 8192;
        int col = o2 >> 7, i = o2 & 127;
        WoT[o2] = f2u(ldr(Wo, (long)i * 64 + col, mode));      // Wo^T[col][i]
    }
}

// ---------------- qkv: MFMA, 64 points/block, 4 waves, B from global ----------------
__global__ __launch_bounds__(256) void qkv_kernel(
    const void* __restrict__ feat, const void* __restrict__ bf1v, const void* __restrict__ WqRaw,
    const u16* __restrict__ WfT, const u16* __restrict__ WqT,
    const u16* __restrict__ WkT, const u16* __restrict__ WvT,
    u16* __restrict__ qw, u16* __restrict__ kfw, u16* __restrict__ vfw) {
    int mode = detect_mode(WqRaw);
    __shared__ __align__(16) u16 sFeat[64 * 72];
    __shared__ __align__(16) u16 sF[64 * SWS];
    const int t = threadIdx.x;
    const int p0 = blockIdx.x * 64;
    const int lane = t & 63, w = t >> 6;
    const int rg = (w & 1) * 32, cg = (w >> 1) * 64;
    const int lm = lane & 15, lq = lane >> 4;

    for (int i = t; i < 512; i += 256) {       // stage feat tile [64x64]
        int r = i >> 3, c8 = i & 7;
        u16 tmp[8];
        if (mode == 0) {
            *(uint4*)tmp = *((const uint4*)feat + (long)(p0 + r) * 8 + c8);
        } else {
            const float* fp = (const float*)feat + (long)(p0 + r) * 64 + c8 * 8;
#pragma unroll
            for (int u = 0; u < 8; ++u) tmp[u] = f2u(fp[u]);
        }
        *(uint4*)(sFeat + r * 72 + c8 * 8) = *(uint4*)tmp;
    }
    __syncthreads();

    // GEMM1: f = feat @ Wf1 + bf1 -> sF   (B from global WfT, stride 64)
    {
        f32x4 acc[2][4];
#pragma unroll
        for (int rt = 0; rt < 2; ++rt)
#pragma unroll
            for (int ct = 0; ct < 4; ++ct) { acc[rt][ct][0]=0.f; acc[rt][ct][1]=0.f; acc[rt][ct][2]=0.f; acc[rt][ct][3]=0.f; }
#pragma unroll
        for (int kk = 0; kk < 2; ++kk) {
            const int ko = kk * 32 + lq * 8;
            bh8 a0 = *(const bh8*)(sFeat + (rg + lm) * 72 + ko);
            bh8 a1 = *(const bh8*)(sFeat + (rg + 16 + lm) * 72 + ko);
            bh8 bq[4];
#pragma unroll
            for (int ct = 0; ct < 4; ++ct)
                bq[ct] = *(const bh8*)(WfT + (long)(cg + ct * 16 + lm) * 64 + ko);
#pragma unroll
            for (int ct = 0; ct < 4; ++ct) {
                acc[0][ct] = __builtin_amdgcn_mfma_f32_16x16x32_bf16(a0, bq[ct], acc[0][ct], 0, 0, 0);
                acc[1][ct] = __builtin_amdgcn_mfma_f32_16x16x32_bf16(a1, bq[ct], acc[1][ct], 0, 0, 0);
            }
        }
#pragma unroll
        for (int rt = 0; rt < 2; ++rt)
#pragma unroll
            for (int ct = 0; ct < 4; ++ct) {
                const int col = cg + ct * 16 + lm;
                const float bj = ldr(bf1v, col, mode);
#pragma unroll
                for (int r4 = 0; r4 < 4; ++r4) {
                    int row = rg + rt * 16 + lq * 4 + r4;
                    u32 u = (u32)f2u(acc[rt][ct][r4] + bj);
                    u32 o = __shfl_xor(u, 1);
                    if ((lane & 1) == 0)
                        *(u32*)(sF + row * SWS + col) = u | (o << 16);
                }
            }
    }
    __syncthreads();

    // GEMM2-4: q/k/v = f @ W   (B from global, stride 128; no more barriers)
    const u16* Ws[3] = {WqT, WkT, WvT};
    u16* Os[3] = {qw, kfw, vfw};
#pragma unroll 1
    for (int m = 0; m < 3; ++m) {
        f32x4 acc[2][4];
#pragma unroll
        for (int rt = 0; rt < 2; ++rt)
#pragma unroll
            for (int ct = 0; ct < 4; ++ct) { acc[rt][ct][0]=0.f; acc[rt][ct][1]=0.f; acc[rt][ct][2]=0.f; acc[rt][ct][3]=0.f; }
#pragma unroll
        for (int kk = 0; kk < 4; ++kk) {
            const int ko = kk * 32 + lq * 8;
            bh8 a0 = *(const bh8*)(sF + (rg + lm) * SWS + ko);
            bh8 a1 = *(const bh8*)(sF + (rg + 16 + lm) * SWS + ko);
            bh8 bq[4];
#pragma unroll
            for (int ct = 0; ct < 4; ++ct)
                bq[ct] = *(const bh8*)(Ws[m] + (long)(cg + ct * 16 + lm) * 128 + ko);
#pragma unroll
            for (int ct = 0; ct < 4; ++ct) {
                acc[0][ct] = __builtin_amdgcn_mfma_f32_16x16x32_bf16(a0, bq[ct], acc[0][ct], 0, 0, 0);
                acc[1][ct] = __builtin_amdgcn_mfma_f32_16x16x32_bf16(a1, bq[ct], acc[1][ct], 0, 0, 0);
            }
        }
#pragma unroll
        for (int rt = 0; rt < 2; ++rt)
#pragma unroll
            for (int ct = 0; ct < 4; ++ct) {
                const int col = cg + ct * 16 + lm;
#pragma unroll
                for (int r4 = 0; r4 < 4; ++r4) {
                    int row = rg + rt * 16 + lq * 4 + r4;
                    u32 u = (u32)f2u(acc[rt][ct][r4]);
                    u32 o = __shfl_xor(u, 1);
                    if ((lane & 1) == 0)
                        *(u32*)(Os[m] + (long)(p0 + row) * DMODEL + col) = u | (o << 16);
                }
            }
    }
}

// ---------------- knn: wave-cooperative top-16, one wave per point ------------------
__global__ __launch_bounds__(256) void knn_kernel(
    const void* __restrict__ xyz, const void* __restrict__ WqRaw, int* __restrict__ knnIdx) {
    int mode = detect_mode(WqRaw);
    __shared__ __align__(8) u16 sXyz[NPTS * 4];
    __shared__ float sN2[NPTS];
    const int t = threadIdx.x;
    const int p0 = blockIdx.x * 4;
    const long xb = (long)(p0 >> 12) * NPTS * 3;
    for (int m = t; m < NPTS; m += 256) {
        float gx = ldr(xyz, xb + m * 3 + 0, mode);
        float gy = ldr(xyz, xb + m * 3 + 1, mode);
        float gz = ldr(xyz, xb + m * 3 + 2, mode);
        uint2 pk;
        pk.x = (u32)f2u(gx) | ((u32)f2u(gy) << 16);
        pk.y = (u32)f2u(gz);
        *(uint2*)(sXyz + m * 4) = pk;
        sN2[m] = gx * gx + gy * gy + gz * gz;
    }
    __syncthreads();
    const int w = t >> 6, lane = t & 63;
    const int pl = (p0 & (NPTS - 1)) + w;
    uint2 qv = *(const uint2*)(sXyz + pl * 4);
    const float px = __uint_as_float(qv.x << 16);
    const float py = __uint_as_float(qv.x & 0xFFFF0000u);
    const float pz = __uint_as_float(qv.y << 16);
    float kd = 3e38f; int ki = 0;
    float T = 3e38f;
#pragma unroll 1
    for (int it = 0; it < NPTS / 64; ++it) {
        const int c = it * 64 + lane;
        uint2 cd = *(const uint2*)(sXyz + c * 4);
        float cx = __uint_as_float(cd.x << 16);
        float cy = __uint_as_float(cd.x & 0xFFFF0000u);
        float cz = __uint_as_float(cd.y << 16);
        float key = sN2[c] - 2.f * (px * cx + py * cy + pz * cz);
        unsigned long long mask = __ballot(key < T);
        while (mask) {
            int l = __ffsll(mask) - 1;
            mask &= mask - 1;
            float kk = __uint_as_float(__builtin_amdgcn_readlane(__float_as_uint(key), l));
            if (kk < T) {
                int ii = it * 64 + l;
                float pkd = __shfl_up(kd, 1);
                int   pki = __shfl_up(ki, 1);
                if (lane == 0) pkd = -3e38f;
                bool pg2 = pkd > kk, cg2 = kd > kk;
                kd = pg2 ? pkd : (cg2 ? kk : kd);
                ki = pg2 ? pki : (cg2 ? ii : ki);
                T = __uint_as_float(__builtin_amdgcn_readlane(__float_as_uint(kd), 15));
            }
        }
    }
    if (lane < 16) knnIdx[(long)(p0 + w) * 16 + lane] = ki;
}

// ---- 4-wave MFMA phase: D[64x128] = sIn @ Bglobal (+bias, opt relu) -> sOut packed
__device__ __forceinline__ void mfma4(const u16* sIn, const u16* __restrict__ Bg,
                                      const float* bias, bool dorelu, bool inplace,
                                      u16* sOut, int t) {
    const int lane = t & 63, w = t >> 6;
    const int rg = (w & 1) * 32, cg = (w >> 1) * 64;
    const int lm = lane & 15, lq = lane >> 4;
    f32x4 acc[2][4];
#pragma unroll
    for (int rt = 0; rt < 2; ++rt)
#pragma unroll
        for (int ct = 0; ct < 4; ++ct) { acc[rt][ct][0]=0.f; acc[rt][ct][1]=0.f; acc[rt][ct][2]=0.f; acc[rt][ct][3]=0.f; }
#pragma unroll
    for (int kk = 0; kk < 4; ++kk) {
        const int ko = kk * 32 + lq * 8;
        bh8 a0 = *(const bh8*)(sIn + (rg + lm) * SWS + ko);
        bh8 a1 = *(const bh8*)(sIn + (rg + 16 + lm) * SWS + ko);
        bh8 bq[4];
#pragma unroll
        for (int ct = 0; ct < 4; ++ct)
            bq[ct] = *(const bh8*)(Bg + (long)(cg + ct * 16 + lm) * 128 + ko);
#pragma unroll
        for (int ct = 0; ct < 4; ++ct) {
            acc[0][ct] = __builtin_amdgcn_mfma_f32_16x16x32_bf16(a0, bq[ct], acc[0][ct], 0, 0, 0);
            acc[1][ct] = __builtin_amdgcn_mfma_f32_16x16x32_bf16(a1, bq[ct], acc[1][ct], 0, 0, 0);
        }
    }
    if (inplace) __syncthreads();
#pragma unroll
    for (int rt = 0; rt < 2; ++rt)
#pragma unroll
        for (int ct = 0; ct < 4; ++ct) {
            const int col = cg + ct * 16 + lm;
            const float bj = bias[col];
#pragma unroll
            for (int r4 = 0; r4 < 4; ++r4) {
                int row = rg + rt * 16 + lq * 4 + r4;
                float v = acc[rt][ct][r4] + bj;
                if (dorelu) v = fmaxf(v, 0.f);
                u32 u = (u32)f2u(v);
                u32 o = __shfl_xor(u, 1);
                if ((lane & 1) == 0)
                    *(u32*)(sOut + row * SWS + col) = u | (o << 16);
            }
        }
}

// ---------------- att: 4 points/block, 4 waves, 38.7KB LDS -> 4 blocks/CU -----------
__global__ __launch_bounds__(256, 4) void att_kernel(
    const void* __restrict__ xyz, const void* __restrict__ feat,
    const void* __restrict__ Wd1, const void* __restrict__ bd1, const void* __restrict__ bd2,
    const void* __restrict__ bg1, const void* __restrict__ bg2, const void* __restrict__ bo,
    const void* __restrict__ WqRaw,
    const u16* __restrict__ WdT2, const u16* __restrict__ WgT1, const u16* __restrict__ WgT2,
    const u16* __restrict__ WoT,
    const u16* __restrict__ qw, const u16* __restrict__ kfw, const u16* __restrict__ vfw,
    const int* __restrict__ knnIdx, void* __restrict__ out) {
    int mode = detect_mode(WqRaw);
    __shared__ __align__(16) u16 sA[64 * SWS];    // H1 -> A -> G -> logits -> res(rows0..3)
    __shared__ __align__(16) u16 sPE[64 * SWS];
    __shared__ __align__(16) float sRel[64][4];
    __shared__ float sBias[3 * DMODEL];
    __shared__ u16 sQ[4 * DMODEL];
    __shared__ int sIdx[64];

    const int t = threadIdx.x, lane = t & 63, w = t >> 6;
    const int p0 = blockIdx.x * 4;
    const long bbase = (long)(p0 >> 12) * NPTS;

    if (t < 64) sIdx[t] = knnIdx[(long)p0 * KNBR + t];
    for (int i = t; i < 384; i += 256) {
        const void* b = (i < 128) ? bd2 : (i < 256) ? bg1 : bg2;
        sBias[i] = ldr(b, i & 127, mode);
    }
    ((u32*)sQ)[t] = ((const u32*)(qw + (long)p0 * DMODEL))[t];
    const int ch = 2 * lane;
    const float wd0a = ldr(Wd1, ch, mode),       wd0b = ldr(Wd1, ch + 1, mode);
    const float wd1a = ldr(Wd1, 128 + ch, mode), wd1b = ldr(Wd1, 128 + ch + 1, mode);
    const float wd2a = ldr(Wd1, 256 + ch, mode), wd2b = ldr(Wd1, 256 + ch + 1, mode);
    const float bd1a = ldr(bd1, ch, mode),       bd1b = ldr(bd1, ch + 1, mode);
    __syncthreads();                              // sIdx ready
    if (t < 64) {
        long nb = bbase + sIdx[t];
        int pl = t >> 4;
        sRel[t][0] = ldr(xyz, ((long)p0 + pl) * 3 + 0, mode) - ldr(xyz, nb * 3 + 0, mode);
        sRel[t][1] = ldr(xyz, ((long)p0 + pl) * 3 + 1, mode) - ldr(xyz, nb * 3 + 1, mode);
        sRel[t][2] = ldr(xyz, ((long)p0 + pl) * 3 + 2, mode) - ldr(xyz, nb * 3 + 2, mode);
    }
    __syncthreads();                              // sRel ready

    // H1 = relu(rel@Wd1+bd1) -> sA (wave w: rows w*16..+15, channel pair ch)
#pragma unroll
    for (int i = 0; i < 16; ++i) {
        int r = w * 16 + i;
        float4 rl = *(const float4*)sRel[r];
        float h0 = fmaxf(bd1a + rl.x * wd0a + rl.y * wd1a + rl.z * wd2a, 0.f);
        float h1 = fmaxf(bd1b + rl.x * wd0b + rl.y * wd1b + rl.z * wd2b, 0.f);
        *(u32*)(sA + r * SWS + ch) = pack2(h0, h1);
    }
    __syncthreads();
    mfma4(sA, WdT2, sBias, false, false, sPE, t);           // PE = H1@Wd2+bd2
    __syncthreads();

    // A = q - kf + pe -> sA
#pragma unroll
    for (int i = 0; i < 16; ++i) {
        int r = w * 16 + i;
        u32 kv2 = *(const u32*)(kfw + (bbase + sIdx[r]) * (long)DMODEL + ch);
        u32 qv2 = *(const u32*)(sQ + (r >> 4) * DMODEL + ch);
        u32 pe2 = *(const u32*)(sPE + r * SWS + ch);
        float a0 = bfu((u16)qv2) - bfu((u16)kv2) + bfu((u16)pe2);
        float a1 = bfu((u16)(qv2 >> 16)) - bfu((u16)(kv2 >> 16)) + bfu((u16)(pe2 >> 16));
        *(u32*)(sA + r * SWS + ch) = pack2(a0, a1);
    }
    __syncthreads();
    mfma4(sA, WgT1, sBias + 128, true, true, sA, t);        // G = relu(A@Wg1+bg1)
    __syncthreads();
    mfma4(sA, WgT2, sBias + 256, false, true, sA, t);       // logits = G@Wg2+bg2
    __syncthreads();

    // softmax over k: wave w = point w, lane = channel pair; res in regs
    float res0, res1;
    {
        float lg0[16], lg1[16];
        float mx0 = -3e38f, mx1 = -3e38f;
#pragma unroll
        for (int k = 0; k < KNBR; ++k) {
            u32 l2 = *(const u32*)(sA + (w * 16 + k) * SWS + ch);
            lg0[k] = bfu((u16)l2); lg1[k] = bfu((u16)(l2 >> 16));
            mx0 = fmaxf(mx0, lg0[k]); mx1 = fmaxf(mx1, lg1[k]);
        }
        const float inv = 0.08838834764831845f;   // 1/sqrt(128)
        float s0 = 0.f, s1 = 0.f, r0 = 0.f, r1 = 0.f;
#pragma unroll
        for (int k = 0; k < KNBR; ++k) {
            u32 v2 = *(const u32*)(vfw + (bbase + sIdx[w * 16 + k]) * (long)DMODEL + ch);
            u32 p2 = *(const u32*)(sPE + (w * 16 + k) * SWS + ch);
            float e0 = __expf((lg0[k] - mx0) * inv);
            float e1 = __expf((lg1[k] - mx1) * inv);
            s0 += e0; s1 += e1;
            r0 += e0 * (bfu((u16)v2) + bfu((u16)p2));
            r1 += e1 * (bfu((u16)(v2 >> 16)) + bfu((u16)(p2 >> 16)));
        }
        res0 = r0 / s0; res1 = r1 / s1;
    }
    __syncthreads();                              // logits reads done
    *(u32*)(sA + w * SWS + ch) = pack2(res0, res1);   // res -> sA rows 0..3
    __syncthreads();

    // out[4x64] = res @ Wo + bo + shortcut (MFMA; A rows 4..15 garbage -> C rows 4..15
    // garbage, discarded: C row r depends only on A row r)
    {
        const int lm = lane & 15, lq = lane >> 4;
        const int col = w * 16 + lm;
        f32x4 acc = {0.f, 0.f, 0.f, 0.f};
#pragma unroll
        for (int kk = 0; kk < 4; ++kk) {
            const int ko = kk * 32 + lq * 8;
            bh8 aa = *(const bh8*)(sA + lm * SWS + ko);
            bh8 bb = *(const bh8*)(WoT + (long)col * DMODEL + ko);
            acc = __builtin_amdgcn_mfma_f32_16x16x32_bf16(aa, bb, acc, 0, 0, 0);
        }
        if (lq == 0) {
            float bov = ldr(bo, col, mode);
#pragma unroll
            for (int r4 = 0; r4 < 4; ++r4) {
                long p = p0 + r4;
                float v = acc[r4] + bov + ldr(feat, p * DPTS + col, mode);
                str(out, p * DPTS + col, v, mode);
            }
        }
    }
}

extern "C" void kernel_launch(void* const* d_in, const int* in_sizes, int n_in,
                              void* d_out, int out_size, void* d_ws, size_t ws_size,
                              hipStream_t stream) {
    (void)in_sizes; (void)n_in; (void)out_size; (void)ws_size;
    char* ws = (char*)d_ws;
    int* idx  = (int*)(ws + 256);
    u16* qw   = (u16*)(ws + 256 + (long)BN * KNBR * 4);
    u16* kfw  = qw + (long)BN * DMODEL;
    u16* vfw  = kfw + (long)BN * DMODEL;
    u16* WdT2 = vfw + (long)BN * DMODEL;
    u16* WgT1 = WdT2 + 16384;
    u16* WgT2 = WgT1 + 16384;
    u16* WoT  = WgT2 + 16384;
    u16* WqT  = WoT + 8192;
    u16* WkT  = WqT + 16384;
    u16* WvT  = WkT + 16384;
    u16* WfT  = WvT + 16384;                  // total ws ~13.6 MB

    prep_kernel<<<448, 256, 0, stream>>>(d_in[4], d_in[11], d_in[13], d_in[15],
                                         d_in[8], d_in[9], d_in[10], d_in[6],
                                         WdT2, WgT1, WgT2, WoT, WqT, WkT, WvT, WfT);
    qkv_kernel<<<BN / 64, 256, 0, stream>>>(d_in[1], d_in[7], d_in[8],
                                            WfT, WqT, WkT, WvT, qw, kfw, vfw);
    knn_kernel<<<BN / 4, 256, 0, stream>>>(d_in[0], d_in[8], idx);
    att_kernel<<<BN / 4, 256, 0, stream>>>(d_in[0], d_in[1], d_in[2], d_in[3], d_in[5],
                                           d_in[12], d_in[14], d_in[16], d_in[8],
                                           WdT2, WgT1, WgT2, WoT,
                                           qw, kfw, vfw, idx, d_out);
}

// Round 8
// 341.053 us; speedup vs baseline: 1.6748x; 1.1315x over previous
//
#include <hip/hip_runtime.h>
#include <hip/hip_bf16.h>

#define NPTS 4096
#define BATCH 4
#define BN (BATCH * NPTS)
#define DMODEL 128
#define DPTS 64
#define KNBR 16
#define SWS 136   // padded LDS row stride in bf16 elements

typedef unsigned short u16;
typedef unsigned int u32;
typedef unsigned long long u64;
typedef short bh8 __attribute__((ext_vector_type(8)));
typedef float f32x4 __attribute__((ext_vector_type(4)));

__device__ __forceinline__ float bfu(u16 u) {
    union { u32 i; float f; } c; c.i = ((u32)u) << 16; return c.f;
}
__device__ __forceinline__ u16 f2u(float x) {   // f32->bf16 RNE
    u32 u = __float_as_uint(x);
    u32 r = u + 0x7FFFu + ((u >> 16) & 1u);
    return (u16)(r >> 16);
}
__device__ __forceinline__ u32 pack2(float a, float b) {
    return (u32)f2u(a) | ((u32)f2u(b) << 16);
}
// mode 0: inputs bf16; mode 1: inputs f32. Runtime-uniform, staging paths only.
__device__ __forceinline__ float ldr(const void* p, long i, int mode) {
    return mode == 0 ? bfu(((const u16*)p)[i]) : ((const float*)p)[i];
}
__device__ __forceinline__ void str(void* p, long i, float v, int mode) {
    if (mode == 0) ((u16*)p)[i] = f2u(v);
    else ((float*)p)[i] = v;
}
// Inline dtype detect: bf16 data has ~0 wild exponent fields; f32-as-u16 has ~84%.
__device__ __forceinline__ int detect_mode(const void* Wq) {
    const u16* w = (const u16*)Wq;
    int lane = threadIdx.x & 63;
    int tot = 0;
#pragma unroll
    for (int r = 0; r < 4; ++r) {
        unsigned e = (w[lane + r * 64] >> 7) & 0xFFu;
        bool wild = (e >= 132u) || (e > 0u && e <= 90u);
        tot += (int)__popcll(__ballot(wild));
    }
    return tot > 32 ? 1 : 0;
}

// ---------------- prep: weight transposes into MFMA B-layouts ------------------------
__global__ __launch_bounds__(256) void prep_kernel(
    const void* __restrict__ Wd2, const void* __restrict__ Wg1, const void* __restrict__ Wg2,
    const void* __restrict__ Wo, const void* __restrict__ Wq, const void* __restrict__ Wk,
    const void* __restrict__ Wv, const void* __restrict__ Wf1,
    u16* __restrict__ WdT2, u16* __restrict__ WgT1, u16* __restrict__ WgT2,
    u16* __restrict__ WoT, u16* __restrict__ WqT, u16* __restrict__ WkT,
    u16* __restrict__ WvT, u16* __restrict__ WfT) {
    int mode = detect_mode(Wq);
    int gid = blockIdx.x * 256 + threadIdx.x;
    if (gid < 6 * 16384) {
        int m = gid >> 14, o = gid & 16383;
        int n = o >> 7, i = o & 127;
        const void* W = (m == 0) ? Wd2 : (m == 1) ? Wg1 : (m == 2) ? Wg2
                      : (m == 3) ? Wq  : (m == 4) ? Wk  : Wv;
        u16* D = (m == 0) ? WdT2 : (m == 1) ? WgT1 : (m == 2) ? WgT2
               : (m == 3) ? WqT  : (m == 4) ? WkT  : WvT;
        D[o] = f2u(ldr(W, (long)i * 128 + n, mode));           // W^T[n][i]
    } else if (gid < 6 * 16384 + 8192) {
        int o = gid - 6 * 16384;
        int n = o >> 6, k2 = o & 63;
        WfT[o] = f2u(ldr(Wf1, (long)k2 * 128 + n, mode));      // Wf1^T[n][k]
    } else if (gid < 6 * 16384 + 16384) {
        int o2 = gid - 6 * 16384 - 8192;
        int col = o2 >> 7, i = o2 & 127;
        WoT[o2] = f2u(ldr(Wo, (long)i * 64 + col, mode));      // Wo^T[col][i]
    }
}

// ---------------- qkv: MFMA, 64 points/block, 4 waves, B from global ----------------
__global__ __launch_bounds__(256) void qkv_kernel(
    const void* __restrict__ feat, const void* __restrict__ bf1v, const void* __restrict__ WqRaw,
    const u16* __restrict__ WfT, const u16* __restrict__ WqT,
    const u16* __restrict__ WkT, const u16* __restrict__ WvT,
    u16* __restrict__ qw, u16* __restrict__ kfw, u16* __restrict__ vfw) {
    int mode = detect_mode(WqRaw);
    __shared__ __align__(16) u16 sFeat[64 * 72];
    __shared__ __align__(16) u16 sF[64 * SWS];
    const int t = threadIdx.x;
    const int p0 = blockIdx.x * 64;
    const int lane = t & 63, w = t >> 6;
    const int rg = (w & 1) * 32, cg = (w >> 1) * 64;
    const int lm = lane & 15, lq = lane >> 4;

    for (int i = t; i < 512; i += 256) {       // stage feat tile [64x64]
        int r = i >> 3, c8 = i & 7;
        u16 tmp[8];
        if (mode == 0) {
            *(uint4*)tmp = *((const uint4*)feat + (long)(p0 + r) * 8 + c8);
        } else {
            const float* fp = (const float*)feat + (long)(p0 + r) * 64 + c8 * 8;
#pragma unroll
            for (int u = 0; u < 8; ++u) tmp[u] = f2u(fp[u]);
        }
        *(uint4*)(sFeat + r * 72 + c8 * 8) = *(uint4*)tmp;
    }
    __syncthreads();

    // GEMM1: f = feat @ Wf1 + bf1 -> sF   (B from global WfT, stride 64)
    {
        f32x4 acc[2][4];
#pragma unroll
        for (int rt = 0; rt < 2; ++rt)
#pragma unroll
            for (int ct = 0; ct < 4; ++ct) { acc[rt][ct][0]=0.f; acc[rt][ct][1]=0.f; acc[rt][ct][2]=0.f; acc[rt][ct][3]=0.f; }
#pragma unroll
        for (int kk = 0; kk < 2; ++kk) {
            const int ko = kk * 32 + lq * 8;
            bh8 a0 = *(const bh8*)(sFeat + (rg + lm) * 72 + ko);
            bh8 a1 = *(const bh8*)(sFeat + (rg + 16 + lm) * 72 + ko);
            bh8 bq[4];
#pragma unroll
            for (int ct = 0; ct < 4; ++ct)
                bq[ct] = *(const bh8*)(WfT + (long)(cg + ct * 16 + lm) * 64 + ko);
#pragma unroll
            for (int ct = 0; ct < 4; ++ct) {
                acc[0][ct] = __builtin_amdgcn_mfma_f32_16x16x32_bf16(a0, bq[ct], acc[0][ct], 0, 0, 0);
                acc[1][ct] = __builtin_amdgcn_mfma_f32_16x16x32_bf16(a1, bq[ct], acc[1][ct], 0, 0, 0);
            }
        }
#pragma unroll
        for (int rt = 0; rt < 2; ++rt)
#pragma unroll
            for (int ct = 0; ct < 4; ++ct) {
                const int col = cg + ct * 16 + lm;
                const float bj = ldr(bf1v, col, mode);
#pragma unroll
                for (int r4 = 0; r4 < 4; ++r4) {
                    int row = rg + rt * 16 + lq * 4 + r4;
                    u32 u = (u32)f2u(acc[rt][ct][r4] + bj);
                    u32 o = __shfl_xor(u, 1);
                    if ((lane & 1) == 0)
                        *(u32*)(sF + row * SWS + col) = u | (o << 16);
                }
            }
    }
    __syncthreads();

    // GEMM2-4: q/k/v = f @ W   (B from global, stride 128)
    const u16* Ws[3] = {WqT, WkT, WvT};
    u16* Os[3] = {qw, kfw, vfw};
#pragma unroll 1
    for (int m = 0; m < 3; ++m) {
        f32x4 acc[2][4];
#pragma unroll
        for (int rt = 0; rt < 2; ++rt)
#pragma unroll
            for (int ct = 0; ct < 4; ++ct) { acc[rt][ct][0]=0.f; acc[rt][ct][1]=0.f; acc[rt][ct][2]=0.f; acc[rt][ct][3]=0.f; }
#pragma unroll
        for (int kk = 0; kk < 4; ++kk) {
            const int ko = kk * 32 + lq * 8;
            bh8 a0 = *(const bh8*)(sF + (rg + lm) * SWS + ko);
            bh8 a1 = *(const bh8*)(sF + (rg + 16 + lm) * SWS + ko);
            bh8 bq[4];
#pragma unroll
            for (int ct = 0; ct < 4; ++ct)
                bq[ct] = *(const bh8*)(Ws[m] + (long)(cg + ct * 16 + lm) * 128 + ko);
#pragma unroll
            for (int ct = 0; ct < 4; ++ct) {
                acc[0][ct] = __builtin_amdgcn_mfma_f32_16x16x32_bf16(a0, bq[ct], acc[0][ct], 0, 0, 0);
                acc[1][ct] = __builtin_amdgcn_mfma_f32_16x16x32_bf16(a1, bq[ct], acc[1][ct], 0, 0, 0);
            }
        }
#pragma unroll
        for (int rt = 0; rt < 2; ++rt)
#pragma unroll
            for (int ct = 0; ct < 4; ++ct) {
                const int col = cg + ct * 16 + lm;
#pragma unroll
                for (int r4 = 0; r4 < 4; ++r4) {
                    int row = rg + rt * 16 + lq * 4 + r4;
                    u32 u = (u32)f2u(acc[rt][ct][r4]);
                    u32 o = __shfl_xor(u, 1);
                    if ((lane & 1) == 0)
                        *(u32*)(Os[m] + (long)(p0 + row) * DMODEL + col) = u | (o << 16);
                }
            }
    }
}

// ---- 4-wave MFMA phase: D[64x128] = sIn @ Bglobal (+bias, opt relu) -> sOut packed
__device__ __forceinline__ void mfma4(const u16* sIn, const u16* __restrict__ Bg,
                                      const float* bias, bool dorelu, bool inplace,
                                      u16* sOut, int t) {
    const int lane = t & 63, w = t >> 6;
    const int rg = (w & 1) * 32, cg = (w >> 1) * 64;
    const int lm = lane & 15, lq = lane >> 4;
    f32x4 acc[2][4];
#pragma unroll
    for (int rt = 0; rt < 2; ++rt)
#pragma unroll
        for (int ct = 0; ct < 4; ++ct) { acc[rt][ct][0]=0.f; acc[rt][ct][1]=0.f; acc[rt][ct][2]=0.f; acc[rt][ct][3]=0.f; }
#pragma unroll
    for (int kk = 0; kk < 4; ++kk) {
        const int ko = kk * 32 + lq * 8;
        bh8 a0 = *(const bh8*)(sIn + (rg + lm) * SWS + ko);
        bh8 a1 = *(const bh8*)(sIn + (rg + 16 + lm) * SWS + ko);
        bh8 bq[4];
#pragma unroll
        for (int ct = 0; ct < 4; ++ct)
            bq[ct] = *(const bh8*)(Bg + (long)(cg + ct * 16 + lm) * 128 + ko);
#pragma unroll
        for (int ct = 0; ct < 4; ++ct) {
            acc[0][ct] = __builtin_amdgcn_mfma_f32_16x16x32_bf16(a0, bq[ct], acc[0][ct], 0, 0, 0);
            acc[1][ct] = __builtin_amdgcn_mfma_f32_16x16x32_bf16(a1, bq[ct], acc[1][ct], 0, 0, 0);
        }
    }
    if (inplace) __syncthreads();
#pragma unroll
    for (int rt = 0; rt < 2; ++rt)
#pragma unroll
        for (int ct = 0; ct < 4; ++ct) {
            const int col = cg + ct * 16 + lm;
            const float bj = bias[col];
#pragma unroll
            for (int r4 = 0; r4 < 4; ++r4) {
                int row = rg + rt * 16 + lq * 4 + r4;
                float v = acc[rt][ct][r4] + bj;
                if (dorelu) v = fmaxf(v, 0.f);
                u32 u = (u32)f2u(v);
                u32 o = __shfl_xor(u, 1);
                if ((lane & 1) == 0)
                    *(u32*)(sOut + row * SWS + col) = u | (o << 16);
            }
        }
}

// ---------------- fused knn+att: 4 points/block, 4 waves, 38.9KB LDS ----------------
// Phase 1: stage 32KB bf16 cloud, wave-per-point top-16 scan (u64 packed key|idx).
// Phase 2: round-7 att pipeline on the same 4 points. Cross-block pipe overlap on CU.
#define ATT_SA 0
#define ATT_SPE 17408
#define ATT_SREL 34816
#define ATT_SBIAS 35840
#define ATT_SQ 37376
#define SMEM_BYTES 38400

__global__ __launch_bounds__(256, 4) void fused_kernel(
    const void* __restrict__ xyz, const void* __restrict__ feat,
    const void* __restrict__ Wd1, const void* __restrict__ bd1, const void* __restrict__ bd2,
    const void* __restrict__ bg1, const void* __restrict__ bg2, const void* __restrict__ bo,
    const void* __restrict__ WqRaw,
    const u16* __restrict__ WdT2, const u16* __restrict__ WgT1, const u16* __restrict__ WgT2,
    const u16* __restrict__ WoT,
    const u16* __restrict__ qw, const u16* __restrict__ kfw, const u16* __restrict__ vfw,
    void* __restrict__ out) {
    int mode = detect_mode(WqRaw);
    __shared__ __align__(16) char smem[SMEM_BYTES];
    __shared__ int sIdx[64];
    u16* sXyz = (u16*)smem;                              // knn view: [4096][4] u16, 32KB
    u16* sA   = (u16*)(smem + ATT_SA);                   // att views
    u16* sPE  = (u16*)(smem + ATT_SPE);
    float (*sRel)[4] = (float(*)[4])(smem + ATT_SREL);
    float* sBias = (float*)(smem + ATT_SBIAS);
    u16* sQ   = (u16*)(smem + ATT_SQ);

    const int t = threadIdx.x, lane = t & 63, w = t >> 6;
    const int p0 = blockIdx.x * 4;
    const long bbase = (long)(p0 >> 12) * NPTS;
    const long xb = bbase * 3;

    // ---- phase 1a: stage cloud as packed bf16 {x|y<<16, z}
    for (int m = t; m < NPTS; m += 256) {
        float gx = ldr(xyz, xb + m * 3 + 0, mode);
        float gy = ldr(xyz, xb + m * 3 + 1, mode);
        float gz = ldr(xyz, xb + m * 3 + 2, mode);
        uint2 pk;
        pk.x = (u32)f2u(gx) | ((u32)f2u(gy) << 16);
        pk.y = (u32)f2u(gz);
        *(uint2*)(sXyz + m * 4) = pk;
    }
    __syncthreads();

    // ---- phase 1b: scan. Wave w = point p0+w. List = one u64/lane, ascending.
    {
        const int pl = (p0 & (NPTS - 1)) + w;
        uint2 qv = *(const uint2*)(sXyz + pl * 4);
        const float px = __uint_as_float(qv.x << 16);
        const float py = __uint_as_float(qv.x & 0xFFFF0000u);
        const float pz = __uint_as_float(qv.y << 16);
        u64 kv = ~0ull;
        u32 Tu = 0xFFFFFFFFu;
        uint2 cd = *(const uint2*)(sXyz + lane * 4);     // prefetch it=0
#pragma unroll 1
        for (int it = 0; it < NPTS / 64; ++it) {
            uint2 cur = cd;
            if (it < NPTS / 64 - 1)
                cd = *(const uint2*)(sXyz + (it + 1) * 256 + lane * 4);
            float cx = __uint_as_float(cur.x << 16);
            float cy = __uint_as_float(cur.x & 0xFFFF0000u);
            float cz = __uint_as_float(cur.y << 16);
            float n2 = cx * cx + cy * cy + cz * cz;
            float dot = px * cx + py * cy + pz * cz;
            float key = fmaf(dot, -2.f, n2);             // d2 - |p|^2
            u32 uk = __float_as_uint(key);
            uk ^= (u32)((int)uk >> 31) | 0x80000000u;    // monotone float->u32
            unsigned long long mask = __ballot(uk < Tu);
            const int ibase = it * 64;
            while (mask) {
                int l = __ffsll(mask) - 1;
                mask &= mask - 1;
                u32 chi = __builtin_amdgcn_readlane(uk, l);
                if (chi < Tu) {                          // uniform branch
                    u64 cand = ((u64)chi << 32) | (u32)(ibase + l);
                    u64 prev = __shfl_up(kv, 1);
                    if (lane == 0) prev = 0;
                    kv = (prev > cand) ? prev : ((kv > cand) ? cand : kv);
                    Tu = __builtin_amdgcn_readlane((u32)(kv >> 32), 15);
                }
            }
        }
        if (lane < 16) sIdx[w * 16 + lane] = (int)(u32)kv;
    }
    __syncthreads();                               // scans done; union region reusable

    // ---- phase 2: att (round-7 pipeline, sIdx from LDS)
    for (int i = t; i < 384; i += 256) {
        const void* b = (i < 128) ? bd2 : (i < 256) ? bg1 : bg2;
        sBias[i] = ldr(b, i & 127, mode);
    }
    ((u32*)sQ)[t] = ((const u32*)(qw + (long)p0 * DMODEL))[t];
    const int ch = 2 * lane;
    const float wd0a = ldr(Wd1, ch, mode),       wd0b = ldr(Wd1, ch + 1, mode);
    const float wd1a = ldr(Wd1, 128 + ch, mode), wd1b = ldr(Wd1, 128 + ch + 1, mode);
    const float wd2a = ldr(Wd1, 256 + ch, mode), wd2b = ldr(Wd1, 256 + ch + 1, mode);
    const float bd1a = ldr(bd1, ch, mode),       bd1b = ldr(bd1, ch + 1, mode);
    if (t < 64) {
        long nb = bbase + sIdx[t];
        int pl2 = t >> 4;
        sRel[t][0] = ldr(xyz, ((long)p0 + pl2) * 3 + 0, mode) - ldr(xyz, nb * 3 + 0, mode);
        sRel[t][1] = ldr(xyz, ((long)p0 + pl2) * 3 + 1, mode) - ldr(xyz, nb * 3 + 1, mode);
        sRel[t][2] = ldr(xyz, ((long)p0 + pl2) * 3 + 2, mode) - ldr(xyz, nb * 3 + 2, mode);
    }
    __syncthreads();                              // sRel/sBias/sQ ready

    // H1 = relu(rel@Wd1+bd1) -> sA (wave w: rows w*16..+15, channel pair ch)
#pragma unroll
    for (int i = 0; i < 16; ++i) {
        int r = w * 16 + i;
        float4 rl = *(const float4*)sRel[r];
        float h0 = fmaxf(bd1a + rl.x * wd0a + rl.y * wd1a + rl.z * wd2a, 0.f);
        float h1 = fmaxf(bd1b + rl.x * wd0b + rl.y * wd1b + rl.z * wd2b, 0.f);
        *(u32*)(sA + r * SWS + ch) = pack2(h0, h1);
    }
    __syncthreads();
    mfma4(sA, WdT2, sBias, false, false, sPE, t);           // PE = H1@Wd2+bd2
    __syncthreads();

    // A = q - kf + pe -> sA
#pragma unroll
    for (int i = 0; i < 16; ++i) {
        int r = w * 16 + i;
        u32 kv2 = *(const u32*)(kfw + (bbase + sIdx[r]) * (long)DMODEL + ch);
        u32 qv2 = *(const u32*)(sQ + (r >> 4) * DMODEL + ch);
        u32 pe2 = *(const u32*)(sPE + r * SWS + ch);
        float a0 = bfu((u16)qv2) - bfu((u16)kv2) + bfu((u16)pe2);
        float a1 = bfu((u16)(qv2 >> 16)) - bfu((u16)(kv2 >> 16)) + bfu((u16)(pe2 >> 16));
        *(u32*)(sA + r * SWS + ch) = pack2(a0, a1);
    }
    __syncthreads();
    mfma4(sA, WgT1, sBias + 128, true, true, sA, t);        // G = relu(A@Wg1+bg1)
    __syncthreads();
    mfma4(sA, WgT2, sBias + 256, false, true, sA, t);       // logits = G@Wg2+bg2
    __syncthreads();

    // softmax over k: wave w = point w, lane = channel pair; res in regs
    float res0, res1;
    {
        float lg0[16], lg1[16];
        float mx0 = -3e38f, mx1 = -3e38f;
#pragma unroll
        for (int k = 0; k < KNBR; ++k) {
            u32 l2 = *(const u32*)(sA + (w * 16 + k) * SWS + ch);
            lg0[k] = bfu((u16)l2); lg1[k] = bfu((u16)(l2 >> 16));
            mx0 = fmaxf(mx0, lg0[k]); mx1 = fmaxf(mx1, lg1[k]);
        }
        const float inv = 0.08838834764831845f;   // 1/sqrt(128)
        float s0 = 0.f, s1 = 0.f, r0 = 0.f, r1 = 0.f;
#pragma unroll
        for (int k = 0; k < KNBR; ++k) {
            u32 v2 = *(const u32*)(vfw + (bbase + sIdx[w * 16 + k]) * (long)DMODEL + ch);
            u32 p2 = *(const u32*)(sPE + (w * 16 + k) * SWS + ch);
            float e0 = __expf((lg0[k] - mx0) * inv);
            float e1 = __expf((lg1[k] - mx1) * inv);
            s0 += e0; s1 += e1;
            r0 += e0 * (bfu((u16)v2) + bfu((u16)p2));
            r1 += e1 * (bfu((u16)(v2 >> 16)) + bfu((u16)(p2 >> 16)));
        }
        res0 = r0 / s0; res1 = r1 / s1;
    }
    __syncthreads();                              // logits reads done
    *(u32*)(sA + w * SWS + ch) = pack2(res0, res1);   // res -> sA rows 0..3
    __syncthreads();

    // out[4x64] = res @ Wo + bo + shortcut (A rows 4..15 garbage -> C rows 4..15
    // garbage, discarded: C row r depends only on A row r)
    {
        const int lm = lane & 15, lq = lane >> 4;
        const int col = w * 16 + lm;
        f32x4 acc = {0.f, 0.f, 0.f, 0.f};
#pragma unroll
        for (int kk = 0; kk < 4; ++kk) {
            const int ko = kk * 32 + lq * 8;
            bh8 aa = *(const bh8*)(sA + lm * SWS + ko);
            bh8 bb = *(const bh8*)(WoT + (long)col * DMODEL + ko);
            acc = __builtin_amdgcn_mfma_f32_16x16x32_bf16(aa, bb, acc, 0, 0, 0);
        }
        if (lq == 0) {
            float bov = ldr(bo, col, mode);
#pragma unroll
            for (int r4 = 0; r4 < 4; ++r4) {
                long p = p0 + r4;
                float v = acc[r4] + bov + ldr(feat, p * DPTS + col, mode);
                str(out, p * DPTS + col, v, mode);
            }
        }
    }
}

extern "C" void kernel_launch(void* const* d_in, const int* in_sizes, int n_in,
                              void* d_out, int out_size, void* d_ws, size_t ws_size,
                              hipStream_t stream) {
    (void)in_sizes; (void)n_in; (void)out_size; (void)ws_size;
    char* ws = (char*)d_ws;
    u16* qw   = (u16*)(ws + 256);
    u16* kfw  = qw + (long)BN * DMODEL;
    u16* vfw  = kfw + (long)BN * DMODEL;
    u16* WdT2 = vfw + (long)BN * DMODEL;
    u16* WgT1 = WdT2 + 16384;
    u16* WgT2 = WgT1 + 16384;
    u16* WoT  = WgT2 + 16384;
    u16* WqT  = WoT + 8192;
    u16* WkT  = WqT + 16384;
    u16* WvT  = WkT + 16384;
    u16* WfT  = WvT + 16384;                  // total ws ~12.7 MB

    prep_kernel<<<448, 256, 0, stream>>>(d_in[4], d_in[11], d_in[13], d_in[15],
                                         d_in[8], d_in[9], d_in[10], d_in[6],
                                         WdT2, WgT1, WgT2, WoT, WqT, WkT, WvT, WfT);
    qkv_kernel<<<BN / 64, 256, 0, stream>>>(d_in[1], d_in[7], d_in[8],
                                            WfT, WqT, WkT, WvT, qw, kfw, vfw);
    fused_kernel<<<BN / 4, 256, 0, stream>>>(d_in[0], d_in[1], d_in[2], d_in[3], d_in[5],
                                             d_in[12], d_in[14], d_in[16], d_in[8],
                                             WdT2, WgT1, WgT2, WoT,
                                             qw, kfw, vfw, d_out);
}